// Round 24
// baseline (209.886 us; speedup 1.0000x reference)
//
#include <hip/hip_runtime.h>
#include <cstdint>
#include <cstddef>

#define NN 20000   // nodes
#define NE 320000  // edges
#define NB 4       // batch
#define NF 16      // f_in
#define NH 64      // hidden
#define NP 12      // periods
#define FP (NF*NP) // 192 features per node row
#define ROWB (FP*2)        // 384 B per (node,batch) sub-row
#define NROWB (NB*ROWB)    // 1536 B per node super-row
#define GRIDA 5000         // k_gather blocks: 20000 waves, 4 (node,batch) units each
#define GRIDG 2500         // k_gru blocks: 10000 waves, 8 units each

typedef _Float16 h2_t __attribute__((ext_vector_type(2)));
typedef _Float16 h4_t __attribute__((ext_vector_type(4)));
typedef float    f4_t __attribute__((ext_vector_type(4)));

union U32H2 { unsigned u; h2_t h; };
union U64H4 { uint2 u; h4_t h; };

// ---------------- convert x to fp16 (interleaved layout) + degree/count --------
// xh layout: [node][batch][192]. Thread <-> (n,c), loop b (r16-verified).
// blocks [0,3750): convert; [3750,5000): degcount.
__global__ __launch_bounds__(256) void k_pre1(const float* __restrict__ x,
                                              _Float16* __restrict__ xh,
                                              const int* __restrict__ ei,
                                              const float* __restrict__ ew,
                                              float* deg, int* counts) {
    int blk = blockIdx.x;
    if (blk < 3750) {
        int i = blk * 256 + threadIdx.x;     // (n,c): n = i/48, c = i%48
        int n = i / 48;
        int c = i - n * 48;
        const float4* xf = (const float4*)x;
        h4_t* xo = (h4_t*)xh;
#pragma unroll
        for (int b = 0; b < NB; ++b) {
            float4 v = xf[(size_t)b * (NN * 48) + i];
            h4_t o = { (_Float16)v.x, (_Float16)v.y, (_Float16)v.z, (_Float16)v.w };
            xo[(n * NB + b) * 48 + c] = o;
        }
    } else {
        int e = (blk - 3750) * 256 + threadIdx.x;
        int dst = ei[NE + e];
        atomicAdd(&deg[dst], ew[e]);
        atomicAdd(&counts[dst], 1);
    }
}

// blocks 0..19: dinv + PARALLEL scan (r17-verified: local LDS scan + atomic
// base -> offsets are an unordered but valid partition; node n owns
// [offsets[n], offsets[n]+counts[n]+1) incl. the self-edge slot).
// block 20: weight folding + GRU B-fragments + output B-fragments + biases.
// H0 == 0 in the reference (carry is the accumulator), so:
//   Z  = sigmoid(a @ (Wg_z @ Wl_z[:64]) + (bg_z @ Wl_z[:64] + bl_z))
//   Ht = tanh  (a @ (Wg_h @ Wl_h[:64]) + (bg_h @ Wl_h[:64] + bl_h))
//   Hn = (1-Z)*Ht          (R path multiplies H0=0 -> dead)
__global__ __launch_bounds__(1024) void k_prep(
        const float* __restrict__ deg, float* __restrict__ dinv,
        const int* __restrict__ counts, int* __restrict__ offsets, int* gbase,
        const float* __restrict__ Wg_z, const float* __restrict__ bg_z,
        const float* __restrict__ Wg_h, const float* __restrict__ bg_h,
        const float* __restrict__ Wl_z, const float* __restrict__ bl_z,
        const float* __restrict__ Wl_h, const float* __restrict__ bl_h,
        const float* __restrict__ att, const float* __restrict__ W_out,
        uint2* __restrict__ wfrag, uint2* __restrict__ wofrag,
        float* bz_eff, float* bh_eff, float* probs) {
    int blk = blockIdx.x;
    int t = threadIdx.x;
    if (blk < 20) {                       // ---- dinv + local scan ----
        __shared__ int sums[1024];
        __shared__ int base_sh;
        int i = blk * 1000 + t;
        int slots = 0;
        if (t < 1000) {
            dinv[i] = rsqrtf(1.0f + deg[i]);          // +1 = self-loop weight
            slots = counts[i] + 1;                    // +1 self-edge slot
        }
        sums[t] = slots;
        __syncthreads();
        for (int off = 1; off < 1024; off <<= 1) {    // inclusive Hillis-Steele
            int v = (t >= off) ? sums[t - off] : 0;
            __syncthreads();
            sums[t] += v;
            __syncthreads();
        }
        if (t == 1023) base_sh = atomicAdd(gbase, sums[1023]);
        __syncthreads();
        if (t < 1000) offsets[i] = base_sh + sums[t] - slots;   // exclusive + base
        return;
    }
    // ---- block 20: weight folding ----  t = f*64 + j
    __shared__ float wzl[NF][NH + 1];
    __shared__ float whl[NF][NH + 1];
    {
        int f = t >> 6, j = t & 63;
        float sz = 0.f, sh = 0.f;
        for (int k = 0; k < NH; ++k) {
            sz += Wg_z[f * NH + k] * Wl_z[k * NH + j];
            sh += Wg_h[f * NH + k] * Wl_h[k * NH + j];
        }
        wzl[f][j] = sz;
        whl[f][j] = sh;
    }
    if (t < NH) {
        float bz = bl_z[t], bh = bl_h[t];
        for (int k = 0; k < NH; ++k) {
            bz += bg_z[k] * Wl_z[k * NH + t];
            bh += bg_h[k] * Wl_h[k * NH + t];
        }
        bz_eff[t] = bz;
        bh_eff[t] = bh;
    }
    if (t == 0) {
        float m = att[0];
        for (int p = 1; p < NP; ++p) m = fmaxf(m, att[p]);
        float s = 0.f, e_[NP];
        for (int p = 0; p < NP; ++p) { e_[p] = expf(att[p] - m); s += e_[p]; }
        for (int p = 0; p < 16; ++p) probs[p] = (p < NP) ? e_[p] / s : 0.f; // [12..15]=0: pad rows
    }
    __syncthreads();
    // ---- GRU B-fragments (z,h): lane ln supplies B[k=4*(ln>>4)+i][n=ln&15], chunk c ----
    if (t < 512) {
        int ln = t & 63, c = (t >> 6) & 3, zh = t >> 8;
        int kb = 4 * (ln >> 4);
        int j  = 16 * c + (ln & 15);
        float v0, v1, v2, v3;
        if (zh == 0) { v0 = wzl[kb][j]; v1 = wzl[kb+1][j]; v2 = wzl[kb+2][j]; v3 = wzl[kb+3][j]; }
        else         { v0 = whl[kb][j]; v1 = whl[kb+1][j]; v2 = whl[kb+2][j]; v3 = whl[kb+3][j]; }
        union { _Float16 h[4]; uint2 u; } pk;
        pk.h[0] = (_Float16)v0; pk.h[1] = (_Float16)v1;
        pk.h[2] = (_Float16)v2; pk.h[3] = (_Float16)v3;
        wfrag[(zh * 4 + c) * 64 + ln] = pk.u;
    }
    // ---- output B-fragments: k-step s, B[k=16s+4*(ln>>4)+i][n=ln&15] = W_out[k][n] ----
    if (t < 256) {
        int ln = t & 63, s = t >> 6;
        int kj = 16 * s + 4 * (ln >> 4);
        int nn_ = ln & 15;
        union { _Float16 h[4]; uint2 u; } pk;
        for (int i = 0; i < 4; ++i)
            pk.h[i] = (_Float16)((nn_ < NP) ? W_out[(kj + i) * NP + nn_] : 0.f);
        wofrag[s * 64 + ln] = pk.u;
    }
}

// edge records {src super-row byte offset (s*1536), f16x2 norm}; threads >= NE
// write the per-node self-edge into slot offsets[node] + counts[node].
__global__ __launch_bounds__(256) void k_fill(const int* __restrict__ ei,
                                              const float* __restrict__ ew,
                                              const float* __restrict__ dinv,
                                              const int* __restrict__ offsets,
                                              const int* __restrict__ counts,
                                              int* cursor, uint2* __restrict__ erec) {
    int e = blockIdx.x * 256 + threadIdx.x;
    if (e < NE) {
        int s = ei[e];
        int d = ei[NE + e];
        float nm = dinv[s] * ew[e] * dinv[d];
        int pos = atomicAdd(&cursor[d], 1);
        int idx = offsets[d] + pos;
        _Float16 hn = (_Float16)nm;
        U32H2 w; w.h = (h2_t){hn, hn};
        erec[idx] = make_uint2((unsigned)(s * NROWB), w.u);
    } else if (e < NE + NN) {
        int node = e - NE;
        float di = dinv[node];
        _Float16 hn = (_Float16)(di * di);
        U32H2 w; w.h = (h2_t){hn, hn};
        erec[offsets[node] + counts[node]] = make_uint2((unsigned)(node * NROWB), w.u);
    }
}

// ---------------- pure gather (r13-proven 75us structure): -> aout ------------
// 20000 waves, 4 units each; wave wv = batch, n = blockIdx + k*GRIDA (block's 4
// waves share node n's 1536B super-row in L2). NO LDS, NO barrier, NO epilogue:
// a wave is always in its load phase. aout[u = wv*NN+n][192] f16, coalesced.
__global__ __launch_bounds__(256) void k_gather(
        const _Float16* __restrict__ xh,
        const int* __restrict__ offsets, const int* __restrict__ counts,
        const uint2* __restrict__ erec, _Float16* __restrict__ aout) {
    int t = threadIdx.x;
    int wv = t >> 6;                            // wave id == batch b
    int lane = t & 63;
    int half = lane >> 5;
    int L = lane & 31;
    int lb0 = L * 12;

    const char* xbase = (const char*)xh;
    int lb = wv * ROWB + lb0;

    for (int k = 0; k < 4; ++k) {
        int n = blockIdx.x + k * GRIDA;         // < NN (4*5000 == 20000)
        int beg = offsets[n];                   // uniform
        int last = beg + counts[n];             // self-edge slot (always valid)
        int end = last + 1;

        h2_t A0 = {(_Float16)0.f, (_Float16)0.f};
        h2_t A1 = A0, A2 = A0;

        // prologue: erec block 0 (8 slots/lane: e + 2k + half, clamped)
        uint2 qa0, qa1, qa2, qa3, qa4, qa5, qa6, qa7;
        {
            int e0 = beg;
#define LQ(K, QV) { int s_ = e0 + 2*(K) + half; int i_ = s_ < last ? s_ : last; QV = erec[i_]; }
            LQ(0,qa0) LQ(1,qa1) LQ(2,qa2) LQ(3,qa3) LQ(4,qa4) LQ(5,qa5) LQ(6,qa6) LQ(7,qa7)
#undef LQ
        }

        int ecur = beg;
        while (true) {
            int enext = ecur + 16;
            bool more = enext < end;          // uniform branch
            uint2 qb0, qb1, qb2, qb3, qb4, qb5, qb6, qb7;
            if (more) {                       // prefetch next erec block
#define LQ(K, QV) { int s_ = enext + 2*(K) + half; int i_ = s_ < last ? s_ : last; QV = erec[i_]; }
                LQ(0,qb0) LQ(1,qb1) LQ(2,qb2) LQ(3,qb3) LQ(4,qb4) LQ(5,qb5) LQ(6,qb6) LQ(7,qb7)
#undef LQ
            }
            // 8 x-row loads (independent, all in flight)
            uint3 u0 = *(const uint3*)(xbase + qa0.x + lb);
            uint3 u1 = *(const uint3*)(xbase + qa1.x + lb);
            uint3 u2 = *(const uint3*)(xbase + qa2.x + lb);
            uint3 u3 = *(const uint3*)(xbase + qa3.x + lb);
            uint3 u4 = *(const uint3*)(xbase + qa4.x + lb);
            uint3 u5 = *(const uint3*)(xbase + qa5.x + lb);
            uint3 u6 = *(const uint3*)(xbase + qa6.x + lb);
            uint3 u7 = *(const uint3*)(xbase + qa7.x + lb);
            // masked accumulate (w=0 for slots past last)
#define ACC(K, QV, UV) { \
                int s_ = ecur + 2*(K) + half; \
                unsigned w_ = (s_ <= last) ? QV.y : 0u; \
                U32H2 wu; wu.u = w_; \
                U32H2 x0; x0.u = UV.x; U32H2 x1; x1.u = UV.y; U32H2 x2; x2.u = UV.z; \
                A0 += wu.h * x0.h; A1 += wu.h * x1.h; A2 += wu.h * x2.h; }
            ACC(0,qa0,u0) ACC(1,qa1,u1) ACC(2,qa2,u2) ACC(3,qa3,u3)
            ACC(4,qa4,u4) ACC(5,qa5,u5) ACC(6,qa6,u6) ACC(7,qa7,u7)
#undef ACC
            if (!more) break;
            qa0=qb0; qa1=qb1; qa2=qb2; qa3=qb3; qa4=qb4; qa5=qb5; qa6=qb6; qa7=qb7;
            ecur = enext;
        }

        // cross-half reduce (3 shfl + 3 pk_add)
        U32H2 t0, t1, t2, s0, s1, s2;
        t0.h = A0; t1.h = A1; t2.h = A2;
        s0.u = (unsigned)__shfl_xor((int)t0.u, 32, 64);
        s1.u = (unsigned)__shfl_xor((int)t1.u, 32, 64);
        s2.u = (unsigned)__shfl_xor((int)t2.u, 32, 64);
        t0.h += s0.h; t1.h += s1.h; t2.h += s2.h;

        // coalesced write: lane L<32 owns f16 elements [6L, 6L+6) of a[u]
        if (lane < 32) {
            uint3 w3; w3.x = t0.u; w3.y = t1.u; w3.z = t2.u;
            *(uint3*)((char*)aout + ((size_t)wv * NN + n) * ROWB + lb0) = w3;
        }
    }
}

// ---------------- dense GRU: aout -> rout (high occupancy, no gather) ---------
// 10000 waves x 8 units. Per unit: coalesced uint3 read of a[u], r21's
// TBAA-safe LDS permute (type-uniform unsigned, parity double-buffer, per-wave
// region), verified MFMA-GRU + transcendental pool + rsel, one f16 store.
__global__ __launch_bounds__(256) void k_gru(
        const _Float16* __restrict__ aout, const uint2* __restrict__ wfrag,
        const float* __restrict__ bz_eff, const float* __restrict__ bh_eff,
        const float* __restrict__ probs, _Float16* __restrict__ rout) {
    __shared__ unsigned a_lds[2][NB][96];       // double-buffered, TYPE-UNIFORM
    __shared__ uint2    wz_lds[512];            // GRU z/h B-fragments
    __shared__ float    bzh_lds[128];           // bz_eff | bh_eff
    __shared__ float    pr_lds[16];

    int t = threadIdx.x;
    wz_lds[t]       = wfrag[t];
    wz_lds[t + 256] = wfrag[t + 256];
    if (t < 128) bzh_lds[t] = (t < 64) ? bz_eff[t] : bh_eff[t - 64];
    if (t < 16)  pr_lds[t] = probs[t];
    __syncthreads();                            // one-time init barrier

    int wv = t >> 6;
    int lane = t & 63;
    int L = lane & 31;
    int g = lane >> 4, p = lane & 15;
    int pe = (p < NP) ? p : 0;
    int q = pe >> 1, hs = pe & 1;

    const char* abase = (const char*)aout;
    int wav = blockIdx.x * 4 + wv;              // 10000 waves

    for (int k = 0, it = 0; k < 8; ++k, ++it) {
        int u = wav + k * 10000;                // 80000 units

        // coalesced read of a[u]: lane L<32 loads 12B (f16 elems [6L, 6L+6))
        uint3 av = make_uint3(0u, 0u, 0u);
        if (lane < 32) av = *(const uint3*)(abase + (size_t)u * ROWB + L * 12);

        // stage into LDS (type-uniform unsigned, parity double-buffer)
        if (lane < 32) {
            unsigned* aw = &a_lds[it & 1][wv][0];
            aw[3 * L + 0] = av.x;
            aw[3 * L + 1] = av.y;
            aw[3 * L + 2] = av.z;
        }
        // same-wave ds_write -> ds_read, same type: dependence TBAA-visible.

        // A-fragment: f16 elem 48g+pe+12i == word 24g+6i+(pe>>1), half pe&1
        const unsigned* abw = &a_lds[it & 1][wv][24 * g + q];
        U32H2 w0; w0.u = abw[0];
        U32H2 w1; w1.u = abw[6];
        U32H2 w2; w2.u = abw[12];
        U32H2 w3; w3.u = abw[18];
        h4_t A = { w0.h[hs], w1.h[hs], w2.h[hs], w3.h[hs] };

        f4_t accz[4], acch[4];
#pragma unroll
        for (int c = 0; c < 4; ++c) {
            float bzv = bzh_lds[16 * c + p];
            float bhv = bzh_lds[64 + 16 * c + p];
            accz[c] = (f4_t){bzv, bzv, bzv, bzv};
            acch[c] = (f4_t){bhv, bhv, bhv, bhv};
        }
#pragma unroll
        for (int c = 0; c < 4; ++c) {
            U64H4 fz; fz.u = wz_lds[c * 64 + lane];
            U64H4 fh; fh.u = wz_lds[(4 + c) * 64 + lane];
            accz[c] = __builtin_amdgcn_mfma_f32_16x16x16f16(A, fz.h, accz[c], 0, 0, 0);
            acch[c] = __builtin_amdgcn_mfma_f32_16x16x16f16(A, fh.h, acch[c], 0, 0, 0);
        }

        // D: lane l, chunk c, reg r -> period p' = 4g+r, hidden j = 16c+p
        float rh0, rh1, rh2, rh3;
#pragma unroll
        for (int c = 0; c < 4; ++c) {
            float partial = 0.f;
#pragma unroll
            for (int r = 0; r < 4; ++r) {
                float zz = accz[c][r];
                float hh = acch[c][r];
                float sn = __builtin_amdgcn_rcpf(1.f + __expf(zz));        // 1-sigmoid(z)
                float th = 1.f - 2.f * __builtin_amdgcn_rcpf(__expf(2.f * hh) + 1.f); // tanh
                partial = fmaf(pr_lds[4 * g + r], sn * th, partial);
            }
            partial += __shfl_xor(partial, 16, 64);   // pool over period groups
            partial += __shfl_xor(partial, 32, 64);
            float v = fmaxf(partial, 0.f);            // relu(H[j=16c+p]), all lanes
            if (c == 0) rh0 = v; else if (c == 1) rh1 = v; else if (c == 2) rh2 = v; else rh3 = v;
        }
        // lane (g,p) stores element j = 16g+p = lane: select chunk c == g (r5-proven)
        float r01 = (g & 1) ? rh1 : rh0;
        float r23 = (g & 1) ? rh3 : rh2;
        float rsel = (g & 2) ? r23 : r01;
        rout[(size_t)u * NH + lane] = (_Float16)rsel;  // 128B/wave coalesced
    }
}

// ---------------- output GEMM: out[u][k] = relu(H)[u] @ W_out + b_out ---------
// u = b*NN + n matches out's [B][N][P] flat layout exactly. 5000 tiles of 16
// rows (batch boundaries tile-aligned: 20000 = 16*1250); wave per tile; 4 MFMAs
// (K=64). A: lane (g,p) reads rout[(u0+p)*64 + 16s+4g .. +3]. D: row 4g+r =
// unit u0+4g+r, col p = out k. (r16/r17/r20/r21/r23 hardware-verified mappings.)
__global__ __launch_bounds__(256) void k_out(
        const _Float16* __restrict__ rout, const uint2* __restrict__ wofrag,
        const float* __restrict__ b_out, float* __restrict__ out) {
    int lane = threadIdx.x & 63;
    int g = lane >> 4, p = lane & 15;
    int tile = blockIdx.x * 4 + (threadIdx.x >> 6);
    int u0 = tile * 16;

    float bo = b_out[p < NP ? p : 0];
    f4_t co = (f4_t){bo, bo, bo, bo};
    const h4_t* arow = (const h4_t*)(rout + (size_t)(u0 + p) * NH);
#pragma unroll
    for (int s = 0; s < 4; ++s) {
        h4_t Ao = arow[4 * s + g];
        U64H4 Bo; Bo.u = wofrag[s * 64 + lane];
        co = __builtin_amdgcn_mfma_f32_16x16x16f16(Ao, Bo.h, co, 0, 0, 0);
    }
    if (p < NP) {
#pragma unroll
        for (int r = 0; r < 4; ++r)
            out[(size_t)(u0 + 4 * g + r) * NP + p] = co[r];
    }
}

// ---------------- launch ----------------

extern "C" void kernel_launch(void* const* d_in, const int* in_sizes, int n_in,
                              void* d_out, int out_size, void* d_ws, size_t ws_size,
                              hipStream_t stream) {
    const float* x     = (const float*)d_in[0];
    const int*   ei    = (const int*)d_in[1];    // int32 per harness (shape [2][NE])
    const float* ew    = (const float*)d_in[2];
    const float* Wg_z  = (const float*)d_in[3];
    const float* bg_z  = (const float*)d_in[4];
    // d_in[5], d_in[6]: Wg_r/bg_r — dead (H0==0)
    const float* Wg_h  = (const float*)d_in[7];
    const float* bg_h  = (const float*)d_in[8];
    const float* Wl_z  = (const float*)d_in[9];
    const float* bl_z  = (const float*)d_in[10];
    // d_in[11], d_in[12]: Wl_r/bl_r — dead
    const float* Wl_h  = (const float*)d_in[13];
    const float* bl_h  = (const float*)d_in[14];
    const float* att   = (const float*)d_in[15];
    const float* W_out = (const float*)d_in[16];
    const float* b_out = (const float*)d_in[17];
    float*       out   = (float*)d_out;

    char* p = (char*)d_ws;
    auto alloc = [&](size_t bytes) -> void* {
        void* r = (void*)p;
        p += (bytes + 255) & ~(size_t)255;
        return r;
    };
    // deg/counts/cursor/gbase contiguous -> one memset zeroes all four
    const size_t PAD_NN = ((size_t)NN * 4 + 255) & ~(size_t)255;
    float*     deg     = (float*)alloc(NN * 4);
    int*       counts  = (int*)  alloc(NN * 4);
    int*       cursor  = (int*)  alloc(NN * 4);
    int*       gbase   = (int*)  alloc(256);
    float*     dinv    = (float*)alloc(NN * 4);
    int*       offsets = (int*)  alloc(NN * 4);
    uint2*     erec    = (uint2*)alloc((size_t)(NE + NN) * 8); // edges + self-edges
    uint2*     wfrag   = (uint2*)alloc(512 * 8);               // GRU z/h B-fragments
    uint2*     wofrag  = (uint2*)alloc(256 * 8);               // output B-fragments
    float*     bz_eff  = (float*)alloc(NH * 4);
    float*     bh_eff  = (float*)alloc(NH * 4);
    float*     probs   = (float*)alloc(16 * 4);
    _Float16*  xh      = (_Float16*)alloc((size_t)NN * NROWB);          // 30.72 MB
    _Float16*  aout    = (_Float16*)alloc((size_t)NN * NROWB);          // 30.72 MB
    _Float16*  rout    = (_Float16*)alloc((size_t)NN * NB * NH * 2);    // 10.24 MB

    hipMemsetAsync(deg, 0, PAD_NN * 3 + 256, stream);

    k_pre1   <<<5000, 256, 0, stream>>>(x, xh, ei, ew, deg, counts);
    k_prep   <<<21, 1024, 0, stream>>>(deg, dinv, counts, offsets, gbase,
                                       Wg_z, bg_z, Wg_h, bg_h, Wl_z, bl_z, Wl_h, bl_h,
                                       att, W_out, wfrag, wofrag, bz_eff, bh_eff, probs);
    k_fill   <<<(NE + NN + 255) / 256, 256, 0, stream>>>(ei, ew, dinv, offsets, counts, cursor, erec);
    k_gather <<<GRIDA, 256, 0, stream>>>(xh, offsets, counts, erec, aout);
    k_gru    <<<GRIDG, 256, 0, stream>>>(aout, wfrag, bz_eff, bh_eff, probs, rout);
    k_out    <<<1250, 256, 0, stream>>>(rout, wofrag, b_out, out);
}

// Round 25
// 176.174 us; speedup vs baseline: 1.1914x; 1.1914x over previous
//
#include <hip/hip_runtime.h>
#include <cstdint>
#include <cstddef>

#define NN 20000   // nodes
#define NE 320000  // edges
#define NB 4       // batch
#define NF 16      // f_in
#define NH 64      // hidden
#define NP 12      // periods
#define FP (NF*NP) // 192 features per node row
#define ROWB (FP*2)        // 384 B per (node,batch) sub-row
#define NROWB (NB*ROWB)    // 1536 B per node super-row
#define GRID_MAIN 2000     // persistent blocks: 10 nodes each

typedef _Float16 h2_t __attribute__((ext_vector_type(2)));
typedef _Float16 h4_t __attribute__((ext_vector_type(4)));
typedef float    f4_t __attribute__((ext_vector_type(4)));

union U32H2 { unsigned u; h2_t h; };
union U64H4 { uint2 u; h4_t h; };

// ---------------- convert x to fp16 (interleaved layout) + degree/count --------
// xh layout: [node][batch][192]. Thread <-> (n,c), loop b (r16-verified).
// blocks [0,3750): convert; [3750,5000): degcount.
__global__ __launch_bounds__(256) void k_pre1(const float* __restrict__ x,
                                              _Float16* __restrict__ xh,
                                              const int* __restrict__ ei,
                                              const float* __restrict__ ew,
                                              float* deg, int* counts) {
    int blk = blockIdx.x;
    if (blk < 3750) {
        int i = blk * 256 + threadIdx.x;     // (n,c): n = i/48, c = i%48
        int n = i / 48;
        int c = i - n * 48;
        const float4* xf = (const float4*)x;
        h4_t* xo = (h4_t*)xh;
#pragma unroll
        for (int b = 0; b < NB; ++b) {
            float4 v = xf[(size_t)b * (NN * 48) + i];
            h4_t o = { (_Float16)v.x, (_Float16)v.y, (_Float16)v.z, (_Float16)v.w };
            xo[(n * NB + b) * 48 + c] = o;
        }
    } else {
        int e = (blk - 3750) * 256 + threadIdx.x;
        int dst = ei[NE + e];
        atomicAdd(&deg[dst], ew[e]);
        atomicAdd(&counts[dst], 1);
    }
}

// blocks 0..19: dinv + PARALLEL scan (r17-verified: local LDS scan + atomic
// base -> offsets are an unordered but valid partition; node n owns
// [offsets[n], offsets[n]+counts[n]+1) incl. the self-edge slot).
// block 20: weight folding + GRU B-fragments + output B-fragments + biases.
// H0 == 0 in the reference (carry is the accumulator), so:
//   Z  = sigmoid(a @ (Wg_z @ Wl_z[:64]) + (bg_z @ Wl_z[:64] + bl_z))
//   Ht = tanh  (a @ (Wg_h @ Wl_h[:64]) + (bg_h @ Wl_h[:64] + bl_h))
//   Hn = (1-Z)*Ht          (R path multiplies H0=0 -> dead)
__global__ __launch_bounds__(1024) void k_prep(
        const float* __restrict__ deg, float* __restrict__ dinv,
        const int* __restrict__ counts, int* __restrict__ offsets, int* gbase,
        const float* __restrict__ Wg_z, const float* __restrict__ bg_z,
        const float* __restrict__ Wg_h, const float* __restrict__ bg_h,
        const float* __restrict__ Wl_z, const float* __restrict__ bl_z,
        const float* __restrict__ Wl_h, const float* __restrict__ bl_h,
        const float* __restrict__ att, const float* __restrict__ W_out,
        uint2* __restrict__ wfrag, uint2* __restrict__ wofrag,
        float* bz_eff, float* bh_eff, float* probs) {
    int blk = blockIdx.x;
    int t = threadIdx.x;
    if (blk < 20) {                       // ---- dinv + local scan ----
        __shared__ int sums[1024];
        __shared__ int base_sh;
        int i = blk * 1000 + t;
        int slots = 0;
        if (t < 1000) {
            dinv[i] = rsqrtf(1.0f + deg[i]);          // +1 = self-loop weight
            slots = counts[i] + 1;                    // +1 self-edge slot
        }
        sums[t] = slots;
        __syncthreads();
        for (int off = 1; off < 1024; off <<= 1) {    // inclusive Hillis-Steele
            int v = (t >= off) ? sums[t - off] : 0;
            __syncthreads();
            sums[t] += v;
            __syncthreads();
        }
        if (t == 1023) base_sh = atomicAdd(gbase, sums[1023]);
        __syncthreads();
        if (t < 1000) offsets[i] = base_sh + sums[t] - slots;   // exclusive + base
        return;
    }
    // ---- block 20: weight folding ----  t = f*64 + j
    __shared__ float wzl[NF][NH + 1];
    __shared__ float whl[NF][NH + 1];
    {
        int f = t >> 6, j = t & 63;
        float sz = 0.f, sh = 0.f;
        for (int k = 0; k < NH; ++k) {
            sz += Wg_z[f * NH + k] * Wl_z[k * NH + j];
            sh += Wg_h[f * NH + k] * Wl_h[k * NH + j];
        }
        wzl[f][j] = sz;
        whl[f][j] = sh;
    }
    if (t < NH) {
        float bz = bl_z[t], bh = bl_h[t];
        for (int k = 0; k < NH; ++k) {
            bz += bg_z[k] * Wl_z[k * NH + t];
            bh += bg_h[k] * Wl_h[k * NH + t];
        }
        bz_eff[t] = bz;
        bh_eff[t] = bh;
    }
    if (t == 0) {
        float m = att[0];
        for (int p = 1; p < NP; ++p) m = fmaxf(m, att[p]);
        float s = 0.f, e_[NP];
        for (int p = 0; p < NP; ++p) { e_[p] = expf(att[p] - m); s += e_[p]; }
        for (int p = 0; p < 16; ++p) probs[p] = (p < NP) ? e_[p] / s : 0.f; // [12..15]=0: pad rows
    }
    __syncthreads();
    // ---- GRU B-fragments (z,h): lane ln supplies B[k=4*(ln>>4)+i][n=ln&15], chunk c ----
    if (t < 512) {
        int ln = t & 63, c = (t >> 6) & 3, zh = t >> 8;
        int kb = 4 * (ln >> 4);
        int j  = 16 * c + (ln & 15);
        float v0, v1, v2, v3;
        if (zh == 0) { v0 = wzl[kb][j]; v1 = wzl[kb+1][j]; v2 = wzl[kb+2][j]; v3 = wzl[kb+3][j]; }
        else         { v0 = whl[kb][j]; v1 = whl[kb+1][j]; v2 = whl[kb+2][j]; v3 = whl[kb+3][j]; }
        union { _Float16 h[4]; uint2 u; } pk;
        pk.h[0] = (_Float16)v0; pk.h[1] = (_Float16)v1;
        pk.h[2] = (_Float16)v2; pk.h[3] = (_Float16)v3;
        wfrag[(zh * 4 + c) * 64 + ln] = pk.u;
    }
    // ---- output B-fragments: k-step s, B[k=16s+4*(ln>>4)+i][n=ln&15] = W_out[k][n] ----
    if (t < 256) {
        int ln = t & 63, s = t >> 6;
        int kj = 16 * s + 4 * (ln >> 4);
        int nn_ = ln & 15;
        union { _Float16 h[4]; uint2 u; } pk;
        for (int i = 0; i < 4; ++i)
            pk.h[i] = (_Float16)((nn_ < NP) ? W_out[(kj + i) * NP + nn_] : 0.f);
        wofrag[s * 64 + ln] = pk.u;
    }
}

// edge records {src super-row byte offset (s*1536), f16x2 norm}; threads >= NE
// write the per-node self-edge into slot offsets[node] + counts[node].
__global__ __launch_bounds__(256) void k_fill(const int* __restrict__ ei,
                                              const float* __restrict__ ew,
                                              const float* __restrict__ dinv,
                                              const int* __restrict__ offsets,
                                              const int* __restrict__ counts,
                                              int* cursor, uint2* __restrict__ erec) {
    int e = blockIdx.x * 256 + threadIdx.x;
    if (e < NE) {
        int s = ei[e];
        int d = ei[NE + e];
        float nm = dinv[s] * ew[e] * dinv[d];
        int pos = atomicAdd(&cursor[d], 1);
        int idx = offsets[d] + pos;
        _Float16 hn = (_Float16)nm;
        U32H2 w; w.h = (h2_t){hn, hn};
        erec[idx] = make_uint2((unsigned)(s * NROWB), w.u);
    } else if (e < NE + NN) {
        int node = e - NE;
        float di = dinv[node];
        _Float16 hn = (_Float16)(di * di);
        U32H2 w; w.h = (h2_t){hn, hn};
        erec[offsets[node] + counts[node]] = make_uint2((unsigned)(node * NROWB), w.u);
    }
}

// ---------------- persistent fused aggregate + MFMA-GRU + attention + output ----
// r17-VERBATIM (best passing, 176.8us total / k_main ~105us). GRID_MAIN blocks
// x 10 nodes; weights preloaded in LDS once; wave b = batch b; masked+
// prefetched 16-edge gather; MFMA GRU; r_lds + one barrier per node; wave-0
// output MFMA writing out directly.
__global__ __launch_bounds__(256) void k_main(
        const _Float16* __restrict__ xh,
        const int* __restrict__ offsets, const int* __restrict__ counts,
        const uint2* __restrict__ erec,
        const uint2* __restrict__ wfrag, const uint2* __restrict__ wofrag,
        const float* __restrict__ bz_eff, const float* __restrict__ bh_eff,
        const float* __restrict__ probs, const float* __restrict__ b_out,
        float* __restrict__ out) {
    __shared__ _Float16 a_lds[NB][FP];          // per-wave aggregated features
    __shared__ _Float16 r_lds[2][NB][NH + 8];   // double-buffered relu(H), padded
    __shared__ uint2    wz_lds[512];            // GRU z/h B-fragments
    __shared__ uint2    wo_lds[256];            // output B-fragments
    __shared__ float    bzh_lds[128];           // bz_eff | bh_eff
    __shared__ float    pr_lds[16];
    __shared__ float    bo_lds[12];

    int t = threadIdx.x;
    wz_lds[t]       = wfrag[t];
    wz_lds[t + 256] = wfrag[t + 256];
    wo_lds[t]       = wofrag[t];
    if (t < 128) bzh_lds[t] = (t < 64) ? bz_eff[t] : bh_eff[t - 64];
    if (t < 16)  pr_lds[t] = probs[t];
    if (t < 12)  bo_lds[t] = b_out[t];
    __syncthreads();

    int b = t >> 6;
    int lane = t & 63;
    int half = lane >> 5;
    int g = lane >> 4, p = lane & 15;

    const char* xbase = (const char*)xh;
    int lb = b * ROWB + (lane & 31) * 12;  // batch offset folded into lane constant

    int it = 0;
    for (int n = blockIdx.x; n < NN; n += GRID_MAIN, ++it) {
        int beg = offsets[n];                 // uniform
        int last = beg + counts[n];           // self-edge slot (always valid)
        int end = last + 1;

        h2_t A0 = {(_Float16)0.f, (_Float16)0.f};
        h2_t A1 = A0, A2 = A0;

        // prologue: erec block 0 (8 slots/lane: e + 2k + half, clamped)
        uint2 qa0, qa1, qa2, qa3, qa4, qa5, qa6, qa7;
        {
            int e0 = beg;
#define LQ(K, QV) { int s_ = e0 + 2*(K) + half; int i_ = s_ < last ? s_ : last; QV = erec[i_]; }
            LQ(0,qa0) LQ(1,qa1) LQ(2,qa2) LQ(3,qa3) LQ(4,qa4) LQ(5,qa5) LQ(6,qa6) LQ(7,qa7)
#undef LQ
        }

        int ecur = beg;
        while (true) {
            int enext = ecur + 16;
            bool more = enext < end;          // uniform branch
            uint2 qb0, qb1, qb2, qb3, qb4, qb5, qb6, qb7;
            if (more) {                       // prefetch next erec block
#define LQ(K, QV) { int s_ = enext + 2*(K) + half; int i_ = s_ < last ? s_ : last; QV = erec[i_]; }
                LQ(0,qb0) LQ(1,qb1) LQ(2,qb2) LQ(3,qb3) LQ(4,qb4) LQ(5,qb5) LQ(6,qb6) LQ(7,qb7)
#undef LQ
            }
            // 8 x-row loads (independent, all in flight)
            uint3 u0 = *(const uint3*)(xbase + qa0.x + lb);
            uint3 u1 = *(const uint3*)(xbase + qa1.x + lb);
            uint3 u2 = *(const uint3*)(xbase + qa2.x + lb);
            uint3 u3 = *(const uint3*)(xbase + qa3.x + lb);
            uint3 u4 = *(const uint3*)(xbase + qa4.x + lb);
            uint3 u5 = *(const uint3*)(xbase + qa5.x + lb);
            uint3 u6 = *(const uint3*)(xbase + qa6.x + lb);
            uint3 u7 = *(const uint3*)(xbase + qa7.x + lb);
            // masked accumulate (w=0 for slots past last)
#define ACC(K, QV, UV) { \
                int s_ = ecur + 2*(K) + half; \
                unsigned w_ = (s_ <= last) ? QV.y : 0u; \
                U32H2 wu; wu.u = w_; \
                U32H2 x0; x0.u = UV.x; U32H2 x1; x1.u = UV.y; U32H2 x2; x2.u = UV.z; \
                A0 += wu.h * x0.h; A1 += wu.h * x1.h; A2 += wu.h * x2.h; }
            ACC(0,qa0,u0) ACC(1,qa1,u1) ACC(2,qa2,u2) ACC(3,qa3,u3)
            ACC(4,qa4,u4) ACC(5,qa5,u5) ACC(6,qa6,u6) ACC(7,qa7,u7)
#undef ACC
            if (!more) break;
            qa0=qb0; qa1=qb1; qa2=qb2; qa3=qb3; qa4=qb4; qa5=qb5; qa6=qb6; qa7=qb7;
            ecur = enext;
        }

        // cross-half reduce (3 shfl + 3 pk_add)
        {
            U32H2 t0, t1, t2, s0, s1, s2;
            t0.h = A0; t1.h = A1; t2.h = A2;
            s0.u = (unsigned)__shfl_xor((int)t0.u, 32, 64);
            s1.u = (unsigned)__shfl_xor((int)t1.u, 32, 64);
            s2.u = (unsigned)__shfl_xor((int)t2.u, 32, 64);
            A0 += s0.h; A1 += s1.h; A2 += s2.h;
        }

        // stage a into LDS (packed); lane L<32 owns elements [6L, 6L+6)
        if (lane < 32) {
            unsigned* aw = (unsigned*)&a_lds[b][0];
            U32H2 t0, t1, t2; t0.h = A0; t1.h = A1; t2.h = A2;
            int L = lane;
            aw[3 * L + 0] = t0.u;
            aw[3 * L + 1] = t1.u;
            aw[3 * L + 2] = t2.u;
        }
        // same-wave ds_write -> ds_read: in program order within a wave

        // A-fragment: A[p][f=4g+i] = a[(4g+i)*12 + p]; pad rows p>=12 clamp to row 0
        int pe = (p < NP) ? p : 0;
        const _Float16* ab = &a_lds[b][48 * g + pe];
        h4_t A = { ab[0], ab[12], ab[24], ab[36] };

        f4_t accz[4], acch[4];
#pragma unroll
        for (int c = 0; c < 4; ++c) {
            float bzv = bzh_lds[16 * c + p];
            float bhv = bzh_lds[64 + 16 * c + p];
            accz[c] = (f4_t){bzv, bzv, bzv, bzv};
            acch[c] = (f4_t){bhv, bhv, bhv, bhv};
        }
#pragma unroll
        for (int c = 0; c < 4; ++c) {
            U64H4 fz; fz.u = wz_lds[c * 64 + lane];
            U64H4 fh; fh.u = wz_lds[(4 + c) * 64 + lane];
            accz[c] = __builtin_amdgcn_mfma_f32_16x16x16f16(A, fz.h, accz[c], 0, 0, 0);
            acch[c] = __builtin_amdgcn_mfma_f32_16x16x16f16(A, fh.h, acch[c], 0, 0, 0);
        }

        // D: lane l, chunk c, reg r -> period p' = 4g+r, hidden j = 16c+p
#pragma unroll
        for (int c = 0; c < 4; ++c) {
            float partial = 0.f;
#pragma unroll
            for (int r = 0; r < 4; ++r) {
                float zz = accz[c][r];
                float hh = acch[c][r];
                float sn = __builtin_amdgcn_rcpf(1.f + __expf(zz));        // 1-sigmoid(z)
                float th = 1.f - 2.f * __builtin_amdgcn_rcpf(__expf(2.f * hh) + 1.f); // tanh
                partial = fmaf(pr_lds[4 * g + r], sn * th, partial);
            }
            partial += __shfl_xor(partial, 16, 64);   // pool over period groups
            partial += __shfl_xor(partial, 32, 64);
            if (g == 0) r_lds[it & 1][b][16 * c + p] = (_Float16)fmaxf(partial, 0.f);
        }
        __syncthreads();

        // wave 0: out[batch][n][k] = r @ W_out + b_out for all 4 batches, 4 MFMAs.
        if (t < 64) {
            float bo = bo_lds[p < NP ? p : 0];
            f4_t co = (f4_t){bo, bo, bo, bo};
            int pb = p & 3;     // batch row (rows 4..15 duplicate -> D rows unread)
#pragma unroll
            for (int s = 0; s < 4; ++s) {
                h4_t Ao = *(const h4_t*)&r_lds[it & 1][pb][16 * s + 4 * g];
                U64H4 Bo; Bo.u = wo_lds[s * 64 + lane];
                co = __builtin_amdgcn_mfma_f32_16x16x16f16(Ao, Bo.h, co, 0, 0, 0);
            }
            // D: col k = p, row = 4g + r = batch; take g==0 lanes
            if (g == 0 && p < NP) {
                size_t baseo = (size_t)n * NP + p;
#pragma unroll
                for (int r = 0; r < 4; ++r)
                    out[(size_t)r * ((size_t)NN * NP) + baseo] = co[r];
            }
        }
    }
}

// ---------------- launch ----------------

extern "C" void kernel_launch(void* const* d_in, const int* in_sizes, int n_in,
                              void* d_out, int out_size, void* d_ws, size_t ws_size,
                              hipStream_t stream) {
    const float* x     = (const float*)d_in[0];
    const int*   ei    = (const int*)d_in[1];    // int32 per harness (shape [2][NE])
    const float* ew    = (const float*)d_in[2];
    const float* Wg_z  = (const float*)d_in[3];
    const float* bg_z  = (const float*)d_in[4];
    // d_in[5], d_in[6]: Wg_r/bg_r — dead (H0==0)
    const float* Wg_h  = (const float*)d_in[7];
    const float* bg_h  = (const float*)d_in[8];
    const float* Wl_z  = (const float*)d_in[9];
    const float* bl_z  = (const float*)d_in[10];
    // d_in[11], d_in[12]: Wl_r/bl_r — dead
    const float* Wl_h  = (const float*)d_in[13];
    const float* bl_h  = (const float*)d_in[14];
    const float* att   = (const float*)d_in[15];
    const float* W_out = (const float*)d_in[16];
    const float* b_out = (const float*)d_in[17];
    float*       out   = (float*)d_out;

    char* p = (char*)d_ws;
    auto alloc = [&](size_t bytes) -> void* {
        void* r = (void*)p;
        p += (bytes + 255) & ~(size_t)255;
        return r;
    };
    // deg/counts/cursor/gbase contiguous -> one memset zeroes all four
    const size_t PAD_NN = ((size_t)NN * 4 + 255) & ~(size_t)255;
    float*     deg     = (float*)alloc(NN * 4);
    int*       counts  = (int*)  alloc(NN * 4);
    int*       cursor  = (int*)  alloc(NN * 4);
    int*       gbase   = (int*)  alloc(256);
    float*     dinv    = (float*)alloc(NN * 4);
    int*       offsets = (int*)  alloc(NN * 4);
    uint2*     erec    = (uint2*)alloc((size_t)(NE + NN) * 8); // edges + self-edges
    uint2*     wfrag   = (uint2*)alloc(512 * 8);               // GRU z/h B-fragments
    uint2*     wofrag  = (uint2*)alloc(256 * 8);               // output B-fragments
    float*     bz_eff  = (float*)alloc(NH * 4);
    float*     bh_eff  = (float*)alloc(NH * 4);
    float*     probs   = (float*)alloc(16 * 4);
    _Float16*  xh      = (_Float16*)alloc((size_t)NN * NROWB); // 30.72 MB interleaved

    hipMemsetAsync(deg, 0, PAD_NN * 3 + 256, stream);

    k_pre1 <<<5000, 256, 0, stream>>>(x, xh, ei, ew, deg, counts);
    k_prep <<<21, 1024, 0, stream>>>(deg, dinv, counts, offsets, gbase,
                                     Wg_z, bg_z, Wg_h, bg_h, Wl_z, bl_z, Wl_h, bl_h,
                                     att, W_out, wfrag, wofrag, bz_eff, bh_eff, probs);
    k_fill <<<(NE + NN + 255) / 256, 256, 0, stream>>>(ei, ew, dinv, offsets, counts, cursor, erec);
    k_main <<<GRID_MAIN, 256, 0, stream>>>(xh, offsets, counts, erec,
                                           wfrag, wofrag, bz_eff, bh_eff, probs, b_out, out);
}